// Round 1
// baseline (77.234 us; speedup 1.0000x reference)
//
#include <hip/hip_runtime.h>
#include <cstdint>
#include <cstddef>

typedef unsigned short u16;
typedef unsigned int u32;
typedef __bf16 bf16x8 __attribute__((ext_vector_type(8)));
typedef float f32x4 __attribute__((ext_vector_type(4)));

#define M_TOT 16384
#define N_TOT 2000
#define K_TOT 512
#define BM 128
#define BN 128
#define BK 32
#define KSTEPS (K_TOT / BK)   // 16

// ---------- f32 -> bf16 (RNE) conversion, 8 elems/thread ----------
__device__ __forceinline__ u16 f2bf(float f) {
  u32 u = __float_as_uint(f);
  u = (u + 0x7FFFu + ((u >> 16) & 1u)) >> 16;
  return (u16)u;
}

__global__ __launch_bounds__(256) void cvt_kernel(const float* __restrict__ src,
                                                  u16* __restrict__ dst, int n8) {
  int i = blockIdx.x * blockDim.x + threadIdx.x;
  if (i >= n8) return;
  const float4* s = (const float4*)src;
  float4 a = s[2 * i], b = s[2 * i + 1];
  ushort4 r0, r1;
  r0.x = f2bf(a.x); r0.y = f2bf(a.y); r0.z = f2bf(a.z); r0.w = f2bf(a.w);
  r1.x = f2bf(b.x); r1.y = f2bf(b.y); r1.z = f2bf(b.z); r1.w = f2bf(b.w);
  ushort4* d = (ushort4*)dst;
  d[2 * i] = r0;
  d[2 * i + 1] = r1;
}

// ---------- async global -> LDS, 16B per lane ----------
__device__ __forceinline__ void gload_lds(const u16* g, u16* l) {
  __builtin_amdgcn_global_load_lds((const __attribute__((address_space(1))) u32*)g,
                                   (__attribute__((address_space(3))) u32*)l, 16, 0, 0);
}

// ---------- main GEMM + fused log_softmax epilogue ----------
// A: x_bf16 [16384][512] row-major; B: W_bf16 [2000][512] row-major (n = c*2+t)
// out[m][n] = logsoftmax over pairs (n even, n odd) of (A.B^T + bias)
__global__ __launch_bounds__(256, 2) void gemm_ls_kernel(const u16* __restrict__ A,
                                                         const u16* __restrict__ B,
                                                         const float* __restrict__ bias,
                                                         float* __restrict__ out) {
  __shared__ u16 As[2][BM * BK];  // 8 KB each
  __shared__ u16 Bs[2][BN * BK];

  const int tid = threadIdx.x;
  const int lane = tid & 63;
  const int w = tid >> 6;          // wave 0..3
  const int wm = w >> 1;           // wave row 0..1
  const int wn = w & 1;            // wave col 0..1
  const int m0 = blockIdx.y * BM;  // 128 m-tiles
  const int n0 = blockIdx.x * BN;  // 16 n-tiles (covers 2048, guard at 2000)

  // ---- staging addresses: tile is 128 rows x 64 bytes; 2 insts/thread ----
  const int off0 = tid * 16;          // byte offset inst 0
  const int off1 = off0 + 4096;       // byte offset inst 1
  const int r0 = off0 >> 6, c0e = (off0 & 63) >> 1;  // row, elem-in-row
  const int r1 = off1 >> 6, c1e = (off1 & 63) >> 1;

  const u16* gA0 = A + (size_t)(m0 + r0) * K_TOT + c0e;
  const u16* gA1 = A + (size_t)(m0 + r1) * K_TOT + c1e;
  int nb0 = n0 + r0; if (nb0 >= N_TOT) nb0 = 0;  // clamp: garbage computed, store-masked
  int nb1 = n0 + r1; if (nb1 >= N_TOT) nb1 = 0;
  const u16* gB0 = B + (size_t)nb0 * K_TOT + c0e;
  const u16* gB1 = B + (size_t)nb1 * K_TOT + c1e;

  u16* lA0[2] = { &As[0][off0 >> 1], &As[1][off0 >> 1] };
  u16* lA1[2] = { &As[0][off1 >> 1], &As[1][off1 >> 1] };
  u16* lB0[2] = { &Bs[0][off0 >> 1], &Bs[1][off0 >> 1] };
  u16* lB1[2] = { &Bs[0][off1 >> 1], &Bs[1][off1 >> 1] };

  f32x4 acc[4][4] = {};

  // prologue: stage k-tile 0 into buf 0
  gload_lds(gA0, lA0[0]);
  gload_lds(gA1, lA1[0]);
  gload_lds(gB0, lB0[0]);
  gload_lds(gB1, lB1[0]);
  __syncthreads();  // drains vmcnt(0)

  const int ar = lane & 15;
  const int kq = (lane >> 4) * 16;  // byte offset of this lane's k-slice (8 bf16)

  int cur = 0;
  for (int kt = 0; kt < KSTEPS; ++kt) {
    if (kt < KSTEPS - 1) {  // issue next-tile loads before compute
      const int ko = (kt + 1) * BK;
      const int nb = cur ^ 1;
      gload_lds(gA0 + ko, lA0[nb]);
      gload_lds(gA1 + ko, lA1[nb]);
      gload_lds(gB0 + ko, lB0[nb]);
      gload_lds(gB1 + ko, lB1[nb]);
    }

    bf16x8 af[4], bf[4];
#pragma unroll
    for (int mi = 0; mi < 4; ++mi) {
      const int row = wm * 64 + mi * 16 + ar;
      af[mi] = *(const bf16x8*)((const char*)&As[cur][0] + row * 64 + kq);
    }
#pragma unroll
    for (int ni = 0; ni < 4; ++ni) {
      const int row = wn * 64 + ni * 16 + ar;
      bf[ni] = *(const bf16x8*)((const char*)&Bs[cur][0] + row * 64 + kq);
    }
#pragma unroll
    for (int mi = 0; mi < 4; ++mi)
#pragma unroll
      for (int ni = 0; ni < 4; ++ni)
        acc[mi][ni] = __builtin_amdgcn_mfma_f32_16x16x32_bf16(af[mi], bf[ni], acc[mi][ni], 0, 0, 0);

    __syncthreads();  // vmcnt(0): next tile landed; all waves done reading cur
    cur ^= 1;
  }

  // ---- epilogue: bias + pairwise log_softmax + store ----
  float bs[4];
  int ncol[4];
#pragma unroll
  for (int ni = 0; ni < 4; ++ni) {
    const int n = n0 + wn * 64 + ni * 16 + ar;
    ncol[ni] = n;
    bs[ni] = (n < N_TOT) ? bias[n] : 0.0f;
  }
  const int rbase = m0 + wm * 64 + (lane >> 4) * 4;

#pragma unroll
  for (int mi = 0; mi < 4; ++mi) {
#pragma unroll
    for (int ni = 0; ni < 4; ++ni) {
#pragma unroll
      for (int j = 0; j < 4; ++j) {
        const float l = acc[mi][ni][j] + bs[ni];
        const float p = __shfl_xor(l, 1);  // partner logit (t pair is adjacent lane)
        const float d = l - p;
        const float o = fminf(d, 0.0f) - __logf(1.0f + __expf(-fabsf(d)));
        if (ncol[ni] < N_TOT) {
          const int row = rbase + mi * 16 + j;
          out[(size_t)row * N_TOT + ncol[ni]] = o;
        }
      }
    }
  }
}

// ---------- naive fp32 fallback (only if ws too small) ----------
__global__ __launch_bounds__(256) void naive_kernel(const float* __restrict__ x,
                                                    const float* __restrict__ W,
                                                    const float* __restrict__ b,
                                                    float* __restrict__ out) {
  __shared__ float xs[K_TOT];
  const int row = blockIdx.x;
  for (int i = threadIdx.x; i < K_TOT; i += 256) xs[i] = x[(size_t)row * K_TOT + i];
  __syncthreads();
  for (int c = threadIdx.x; c < 1000; c += 256) {
    const float* w0 = W + (size_t)c * 1024;
    float l0 = b[c * 2], l1 = b[c * 2 + 1];
    for (int k = 0; k < K_TOT; ++k) {
      const float xv = xs[k];
      l0 += xv * w0[k];
      l1 += xv * w0[K_TOT + k];
    }
    const float d = l0 - l1;
    const float t = __logf(1.0f + __expf(-fabsf(d)));
    out[(size_t)row * N_TOT + c * 2]     = fminf(d, 0.0f) - t;
    out[(size_t)row * N_TOT + c * 2 + 1] = fminf(-d, 0.0f) - t;
  }
}

extern "C" void kernel_launch(void* const* d_in, const int* in_sizes, int n_in,
                              void* d_out, int out_size, void* d_ws, size_t ws_size,
                              hipStream_t stream) {
  const float* x = (const float*)d_in[0];   // [16384, 512]
  const float* W = (const float*)d_in[1];   // [1000, 2, 512] == [2000, 512] row-major
  const float* b = (const float*)d_in[2];   // [1000, 2] == [2000]
  float* out = (float*)d_out;               // [16384, 1000, 2]

  const size_t nx = (size_t)M_TOT * K_TOT;      // 8388608
  const size_t nw = (size_t)N_TOT * K_TOT;      // 1024000
  const size_t need = (nx + nw) * sizeof(u16);  // ~18.8 MB

  if (ws_size < need) {
    naive_kernel<<<M_TOT, 256, 0, stream>>>(x, W, b, out);
    return;
  }

  u16* xb = (u16*)d_ws;
  u16* wb = xb + nx;

  cvt_kernel<<<(int)(nx / 8 + 255) / 256, 256, 0, stream>>>(x, xb, (int)(nx / 8));
  cvt_kernel<<<(int)(nw / 8 + 255) / 256, 256, 0, stream>>>(W, wb, (int)(nw / 8));

  dim3 grid(BN == 128 ? 16 : (N_TOT + BN - 1) / BN, M_TOT / BM);  // (16, 128)
  gemm_ls_kernel<<<grid, 256, 0, stream>>>(xb, wb, b, out);
}

// Round 2
// 58.674 us; speedup vs baseline: 1.3163x; 1.3163x over previous
//
#include <hip/hip_runtime.h>
#include <cstdint>
#include <cstddef>

typedef unsigned short u16;
typedef unsigned int u32;
typedef __bf16 bf16x8 __attribute__((ext_vector_type(8)));
typedef float f32x4 __attribute__((ext_vector_type(4)));

#define M_TOT 16384
#define C_TOT 1000        // classes = GEMM N dimension
#define N_PAD 1024        // padded B rows
#define K_TOT 512
#define OUT_STRIDE 2000   // out row stride in floats (1000 classes x 2)
#define BM 128
#define BN 128
#define BK 32
#define KSTEPS (K_TOT / BK)   // 16

// ---------- f32 -> bf16 (RNE) ----------
__device__ __forceinline__ u16 f2bf(float f) {
  u32 u = __float_as_uint(f);
  u = (u + 0x7FFFu + ((u >> 16) & 1u)) >> 16;
  return (u16)u;
}

// x: f32 -> bf16, 8 elems/thread
__global__ __launch_bounds__(256) void cvt_kernel(const float* __restrict__ src,
                                                  u16* __restrict__ dst, int n8) {
  int i = blockIdx.x * blockDim.x + threadIdx.x;
  if (i >= n8) return;
  const float4* s = (const float4*)src;
  float4 a = s[2 * i], b = s[2 * i + 1];
  ushort4 r0, r1;
  r0.x = f2bf(a.x); r0.y = f2bf(a.y); r0.z = f2bf(a.z); r0.w = f2bf(a.w);
  r1.x = f2bf(b.x); r1.y = f2bf(b.y); r1.z = f2bf(b.z); r1.w = f2bf(b.w);
  ushort4* d = (ushort4*)dst;
  d[2 * i] = r0;
  d[2 * i + 1] = r1;
}

// Wdiff[c,:] = bf16(W[c,0,:] - W[c,1,:]), rows >= C_TOT zero-padded; bdiff[c] = b[2c]-b[2c+1]
__global__ __launch_bounds__(256) void wdiff_kernel(const float* __restrict__ W,
                                                    const float* __restrict__ b,
                                                    u16* __restrict__ wd,
                                                    float* __restrict__ bd) {
  const int i = blockIdx.x * blockDim.x + threadIdx.x;  // 65536 threads
  const int c = i >> 6;        // row 0..1023
  const int seg = i & 63;      // 8-elem segment within the 512-wide row
  if (c >= N_PAD) return;
  ushort4 r0 = {0, 0, 0, 0}, r1 = {0, 0, 0, 0};
  if (c < C_TOT) {
    const float4* w0 = (const float4*)(W + (size_t)(2 * c) * K_TOT) + seg * 2;
    const float4* w1 = (const float4*)(W + (size_t)(2 * c + 1) * K_TOT) + seg * 2;
    float4 a0 = w0[0], a1 = w0[1], c0 = w1[0], c1 = w1[1];
    r0.x = f2bf(a0.x - c0.x); r0.y = f2bf(a0.y - c0.y);
    r0.z = f2bf(a0.z - c0.z); r0.w = f2bf(a0.w - c0.w);
    r1.x = f2bf(a1.x - c1.x); r1.y = f2bf(a1.y - c1.y);
    r1.z = f2bf(a1.z - c1.z); r1.w = f2bf(a1.w - c1.w);
    if (seg == 0) bd[c] = b[2 * c] - b[2 * c + 1];
  } else if (seg == 0) {
    bd[c] = 0.0f;
  }
  ushort4* d = (ushort4*)(wd + (size_t)c * K_TOT);
  d[seg * 2] = r0;
  d[seg * 2 + 1] = r1;
}

// ---------- async global -> LDS, 16B per lane ----------
__device__ __forceinline__ void gload_lds(const u16* g, u16* l) {
  __builtin_amdgcn_global_load_lds((const __attribute__((address_space(1))) u32*)g,
                                   (__attribute__((address_space(3))) u32*)l, 16, 0, 0);
}

// ---------- GEMM (M=16384, N=1024pad, K=512) + fused pairwise log_softmax ----------
// A: x_bf16 [M][512]; B: Wdiff_bf16 [1024][512]; d = A.B^T + bdiff
// out[m][2c+0] = min(d,0)-log1p(exp(-|d|)); out[m][2c+1] = out0 - d
__global__ __launch_bounds__(256, 2) void gemm_ls_kernel(const u16* __restrict__ A,
                                                         const u16* __restrict__ B,
                                                         const float* __restrict__ bdiff,
                                                         float* __restrict__ out) {
  __shared__ u16 As[2][BM * BK];  // 8 KB each
  __shared__ u16 Bs[2][BN * BK];

  const int tid = threadIdx.x;
  const int lane = tid & 63;
  const int w = tid >> 6;          // wave 0..3
  const int wm = w >> 1;           // wave row 0..1
  const int wn = w & 1;            // wave col 0..1
  const int m0 = blockIdx.y * BM;  // 128 m-tiles
  const int n0 = blockIdx.x * BN;  // 8 n-tiles (covers 1024 padded)

  // staging: tile is 128 rows x 64 bytes; 256 threads x 16B x 2 insts
  const int off0 = tid * 16;
  const int off1 = off0 + 4096;
  const int r0 = off0 >> 6, c0e = (off0 & 63) >> 1;
  const int r1 = off1 >> 6, c1e = (off1 & 63) >> 1;

  const u16* gA0 = A + (size_t)(m0 + r0) * K_TOT + c0e;
  const u16* gA1 = A + (size_t)(m0 + r1) * K_TOT + c1e;
  const u16* gB0 = B + (size_t)(n0 + r0) * K_TOT + c0e;  // padded: unguarded
  const u16* gB1 = B + (size_t)(n0 + r1) * K_TOT + c1e;

  u16* lA0[2] = { &As[0][off0 >> 1], &As[1][off0 >> 1] };
  u16* lA1[2] = { &As[0][off1 >> 1], &As[1][off1 >> 1] };
  u16* lB0[2] = { &Bs[0][off0 >> 1], &Bs[1][off0 >> 1] };
  u16* lB1[2] = { &Bs[0][off1 >> 1], &Bs[1][off1 >> 1] };

  f32x4 acc[4][4] = {};

  gload_lds(gA0, lA0[0]);
  gload_lds(gA1, lA1[0]);
  gload_lds(gB0, lB0[0]);
  gload_lds(gB1, lB1[0]);
  __syncthreads();

  const int ar = lane & 15;
  const int kq = (lane >> 4) * 16;

  int cur = 0;
  for (int kt = 0; kt < KSTEPS; ++kt) {
    if (kt < KSTEPS - 1) {
      const int ko = (kt + 1) * BK;
      const int nb = cur ^ 1;
      gload_lds(gA0 + ko, lA0[nb]);
      gload_lds(gA1 + ko, lA1[nb]);
      gload_lds(gB0 + ko, lB0[nb]);
      gload_lds(gB1 + ko, lB1[nb]);
    }

    bf16x8 af[4], bf[4];
#pragma unroll
    for (int mi = 0; mi < 4; ++mi) {
      const int row = wm * 64 + mi * 16 + ar;
      af[mi] = *(const bf16x8*)((const char*)&As[cur][0] + row * 64 + kq);
    }
#pragma unroll
    for (int ni = 0; ni < 4; ++ni) {
      const int row = wn * 64 + ni * 16 + ar;
      bf[ni] = *(const bf16x8*)((const char*)&Bs[cur][0] + row * 64 + kq);
    }
#pragma unroll
    for (int mi = 0; mi < 4; ++mi)
#pragma unroll
      for (int ni = 0; ni < 4; ++ni)
        acc[mi][ni] = __builtin_amdgcn_mfma_f32_16x16x32_bf16(af[mi], bf[ni], acc[mi][ni], 0, 0, 0);

    __syncthreads();
    cur ^= 1;
  }

  // ---- epilogue: d -> (o0, o1) float2 store ----
  float bd_r[4];
  int ncol[4];
#pragma unroll
  for (int ni = 0; ni < 4; ++ni) {
    const int n = n0 + wn * 64 + ni * 16 + ar;   // < 1024 always
    ncol[ni] = n;
    bd_r[ni] = bdiff[n];
  }
  const int rbase = m0 + wm * 64 + (lane >> 4) * 4;

#pragma unroll
  for (int mi = 0; mi < 4; ++mi) {
#pragma unroll
    for (int ni = 0; ni < 4; ++ni) {
      if (ncol[ni] < C_TOT) {
#pragma unroll
        for (int j = 0; j < 4; ++j) {
          const float d = acc[mi][ni][j] + bd_r[ni];
          const float o0 = fminf(d, 0.0f) - __logf(1.0f + __expf(-fabsf(d)));
          const int row = rbase + mi * 16 + j;
          float2 v;
          v.x = o0;
          v.y = o0 - d;
          *(float2*)(out + (size_t)row * OUT_STRIDE + 2 * ncol[ni]) = v;
        }
      }
    }
  }
}

// ---------- naive fp32 fallback (only if ws too small) ----------
__global__ __launch_bounds__(256) void naive_kernel(const float* __restrict__ x,
                                                    const float* __restrict__ W,
                                                    const float* __restrict__ b,
                                                    float* __restrict__ out) {
  __shared__ float xs[K_TOT];
  const int row = blockIdx.x;
  for (int i = threadIdx.x; i < K_TOT; i += 256) xs[i] = x[(size_t)row * K_TOT + i];
  __syncthreads();
  for (int c = threadIdx.x; c < C_TOT; c += 256) {
    const float* w0 = W + (size_t)c * 1024;
    float l0 = b[c * 2], l1 = b[c * 2 + 1];
    for (int k = 0; k < K_TOT; ++k) {
      const float xv = xs[k];
      l0 += xv * w0[k];
      l1 += xv * w0[K_TOT + k];
    }
    const float d = l0 - l1;
    const float t = __logf(1.0f + __expf(-fabsf(d)));
    out[(size_t)row * OUT_STRIDE + c * 2]     = fminf(d, 0.0f) - t;
    out[(size_t)row * OUT_STRIDE + c * 2 + 1] = fminf(-d, 0.0f) - t;
  }
}

extern "C" void kernel_launch(void* const* d_in, const int* in_sizes, int n_in,
                              void* d_out, int out_size, void* d_ws, size_t ws_size,
                              hipStream_t stream) {
  const float* x = (const float*)d_in[0];   // [16384, 512]
  const float* W = (const float*)d_in[1];   // [1000, 2, 512]
  const float* b = (const float*)d_in[2];   // [1000, 2]
  float* out = (float*)d_out;               // [16384, 1000, 2]

  const size_t nx = (size_t)M_TOT * K_TOT;                  // 8388608 elems
  const size_t nwd = (size_t)N_PAD * K_TOT;                 // 524288 elems
  const size_t need = (nx + nwd) * sizeof(u16) + N_PAD * sizeof(float);

  if (ws_size < need) {
    naive_kernel<<<M_TOT, 256, 0, stream>>>(x, W, b, out);
    return;
  }

  u16* xb = (u16*)d_ws;
  u16* wd = xb + nx;
  float* bd = (float*)(wd + nwd);

  cvt_kernel<<<(int)(nx / 8 + 255) / 256, 256, 0, stream>>>(x, xb, (int)(nx / 8));
  wdiff_kernel<<<(N_PAD * 64) / 256, 256, 0, stream>>>(W, b, wd, bd);

  dim3 grid(N_PAD / BN, M_TOT / BM);  // (8, 128)
  gemm_ls_kernel<<<grid, 256, 0, stream>>>(xb, wd, bd, out);
}